// Round 1
// baseline (879.835 us; speedup 1.0000x reference)
//
#include <hip/hip_runtime.h>
#include <math.h>

#define P 128
#define T_WIN 480
#define STEPD 20
#define LAG_W 24
#define CHUNK 32
#define NCHUNK (T_WIN / CHUNK)

// ---------------- kernel 0: EWMA weights (fp64, one block) ----------------
__global__ __launch_bounds__(512) void weights_kernel(const float* __restrict__ a,
                                                      float* __restrict__ wbuf) {
  __shared__ double redd[512];
  const int t = threadIdx.x;
  const double la = log((double)a[0]);
  const double r = (t < T_WIN) ? exp((double)(T_WIN - 1 - t) * la) : 0.0;
  redd[t] = r;
  __syncthreads();
  for (int off = 256; off > 0; off >>= 1) {
    if (t < off) redd[t] += redd[t + off];
    __syncthreads();
  }
  const double S = redd[0];
  __syncthreads();
  const double wt = r / S * (double)T_WIN;
  redd[t] = wt * wt;
  __syncthreads();
  for (int off = 256; off > 0; off >>= 1) {
    if (t < off) redd[t] += redd[t + off];
    __syncthreads();
  }
  if (t < T_WIN) {
    wbuf[t] = (float)wt;                 // w_t (normalized, sum = T)
    wbuf[T_WIN + t] = (float)sqrt(wt);   // sqrt(w_t) for syrk staging
  }
  if (t == 0) {
    wbuf[2 * T_WIN] = (float)(1.0 - redd[0] / ((double)T_WIN * (double)T_WIN)); // denom
  }
}

// ---------------- kernel 1: one block per window ----------------
__global__ __launch_bounds__(256, 2) void window_kernel(
    const float* __restrict__ Y, const float* __restrict__ wbuf,
    const float* __restrict__ logridge, float* __restrict__ e_all,
    float* __restrict__ s_all, int W) {
  const int j = blockIdx.x;
  const int tid = threadIdx.x;
  const int ti = tid >> 4;   // 0..15
  const int tj = tid & 15;   // 0..15

  __shared__ float Msm[P][P + 1];   // 66 KB; first 16 KB reused as staging buffer
  __shared__ float wsm[T_WIN];
  __shared__ float swsm[T_WIN];
  __shared__ float meansm[P];
  __shared__ float red[256];
  __shared__ float retd[STEPD];
  __shared__ float zsm[P];
  __shared__ float vsm[P];
  __shared__ float bsm[P];

  float* stage = &Msm[0][0];  // CHUNK*P = 4096 floats, fits inside Msm

  // load weights into LDS
  for (int t = tid; t < T_WIN; t += 256) {
    wsm[t] = wbuf[t];
    swsm[t] = wbuf[T_WIN + t];
  }
  if (tid < P) bsm[tid] = 1.0f;
  const float denom = wbuf[2 * T_WIN];
  const float ridge = expf(logridge[0]);
  __syncthreads();

  const float* __restrict__ Ywin = Y + (size_t)j * STEPD * P;

  // ---- weighted mean: mean[p] = sum_t w_t Y[t,p] / T ----
  {
    const int col = tid & 127;
    const int half = tid >> 7;  // 0/1
    float m = 0.0f;
    const int t0 = half * (T_WIN / 2), t1 = t0 + T_WIN / 2;
    for (int t = t0; t < t1; ++t) m += wsm[t] * Ywin[(size_t)t * P + col];
    red[tid] = m;
    __syncthreads();
    if (tid < P) meansm[tid] = (red[tid] + red[tid + 128]) * (1.0f / (float)T_WIN);
    __syncthreads();
  }

  // ---- A = sum_t w_t y y^T  via syrk on sqrt(w)-scaled rows ----
  float acc[8][8];
#pragma unroll
  for (int u = 0; u < 8; ++u)
#pragma unroll
    for (int v = 0; v < 8; ++v) acc[u][v] = 0.0f;

  for (int c = 0; c < NCHUNK; ++c) {
    __syncthreads();  // protect stage region (aliases Msm)
#pragma unroll
    for (int i = 0; i < 4; ++i) {
      const int idx = i * 1024 + tid * 4;
      float4 v = *(const float4*)(Ywin + (size_t)c * CHUNK * P + idx);
      const int t = c * CHUNK + (idx >> 7);
      const float sw = swsm[t];
      v.x *= sw; v.y *= sw; v.z *= sw; v.w *= sw;
      *(float4*)(stage + idx) = v;
    }
    __syncthreads();
#pragma unroll 4
    for (int t = 0; t < CHUNK; ++t) {
      const float* rowp = stage + t * P;
      float af[8], bf[8];
      *(float4*)(af) = *(const float4*)(rowp + ti * 8);
      *(float4*)(af + 4) = *(const float4*)(rowp + ti * 8 + 4);
      *(float4*)(bf) = *(const float4*)(rowp + tj * 8);
      *(float4*)(bf + 4) = *(const float4*)(rowp + tj * 8 + 4);
#pragma unroll
      for (int u = 0; u < 8; ++u)
#pragma unroll
        for (int v = 0; v < 8; ++v) acc[u][v] += af[u] * bf[v];
    }
  }
  __syncthreads();

  // ---- M = (A - T mean mean^T)/(T denom) + ridge I ----
  const float invTd = 1.0f / ((float)T_WIN * denom);
#pragma unroll
  for (int u = 0; u < 8; ++u) {
    const int r = ti * 8 + u;
    const float mr = meansm[r];
#pragma unroll
    for (int v = 0; v < 8; ++v) {
      const int cc = tj * 8 + v;
      float m = (acc[u][v] - (float)T_WIN * mr * meansm[cc]) * invTd;
      if (r == cc) m += ridge;
      Msm[r][cc] = m;
    }
  }
  __syncthreads();

  // ---- Cholesky (lower, in place; full-square symmetric trailing update) ----
  for (int k = 0; k < P; ++k) {
    const float dkk = Msm[k][k];
    const float sq = sqrtf(dkk);
    const float invd = 1.0f / sq;
    if (tid == 0) Msm[k][k] = sq;
    const int i = k + 1 + tid;
    if (i < P) Msm[i][k] *= invd;
    __syncthreads();
    const int nrem = P - 1 - k;
    for (int ii = ti; ii < nrem; ii += 16) {
      const int ri = k + 1 + ii;
      const float Lik = Msm[ri][k];
      for (int jj = tj; jj < nrem; jj += 16) {
        const int cj = k + 1 + jj;
        Msm[ri][cj] -= Lik * Msm[cj][k];
      }
    }
    __syncthreads();
  }

  // ---- forward solve L z = 1 ----
  for (int k = 0; k < P; ++k) {
    const float zk = bsm[k] / Msm[k][k];
    if (tid == 0) zsm[k] = zk;
    const int i = k + 1 + tid;
    if (i < P) bsm[i] -= Msm[i][k] * zk;
    __syncthreads();
  }

  // ---- back solve L^T v = z ----
  for (int k = P - 1; k >= 0; --k) {
    const float vk = zsm[k] / Msm[k][k];
    if (tid == 0) vsm[k] = vk;
    if (tid < k) zsm[tid] -= Msm[k][tid] * vk;
    __syncthreads();
  }

  // ---- sum(v) ----
  red[tid] = (tid < P) ? vsm[tid] : 0.0f;
  __syncthreads();
  for (int off = 128; off > 0; off >>= 1) {
    if (tid < off) red[tid] += red[tid + off];
    __syncthreads();
  }

  // ---- test returns: ret_d = (Yte[d] . v) / sum(v) ----
  const float* __restrict__ Yte = Y + (size_t)(j + LAG_W) * STEPD * P;
  const int wv = tid >> 6;
  const int lane = tid & 63;
  for (int d = wv; d < STEPD; d += 4) {
    float pp = Yte[(size_t)d * P + lane] * vsm[lane] +
               Yte[(size_t)d * P + 64 + lane] * vsm[64 + lane];
    for (int off = 32; off > 0; off >>= 1) pp += __shfl_down(pp, off);
    if (lane == 0) retd[d] = pp;
  }
  __syncthreads();

  if (tid == 0) {
    const float invs = 1.0f / red[0];
    float e = 0.0f, s = 0.0f;
#pragma unroll
    for (int d = 0; d < STEPD; ++d) {
      const float r = retd[d] * invs;
      e += r;
      s += r * r;
    }
    e_all[j] = e;
    s_all[j] = s * (1.0f / (float)STEPD);
  }
}

// ---------------- kernel 2: final reduction ----------------
__global__ __launch_bounds__(256) void final_kernel(const float* __restrict__ e_all,
                                                    const float* __restrict__ s_all,
                                                    float* __restrict__ out, int W) {
  __shared__ float r1[256], r2[256];
  const int tid = threadIdx.x;
  float e = 0.0f, s = 0.0f;
  for (int i = tid; i < W; i += 256) {
    e += e_all[i];
    s += s_all[i];
  }
  r1[tid] = e;
  r2[tid] = s;
  __syncthreads();
  for (int off = 128; off > 0; off >>= 1) {
    if (tid < off) {
      r1[tid] += r1[tid + off];
      r2[tid] += r2[tid + off];
    }
    __syncthreads();
  }
  if (tid == 0) {
    const float vol = sqrtf(r2[0] / (float)W * 252.0f);
    const float mu = r1[0] / (float)W / (float)STEPD * 252.0f;
    out[0] = vol;
    out[1] = mu;
    out[2] = mu / vol;
  }
}

extern "C" void kernel_launch(void* const* d_in, const int* in_sizes, int n_in,
                              void* d_out, int out_size, void* d_ws, size_t ws_size,
                              hipStream_t stream) {
  const float* Y = (const float*)d_in[0];
  const float* a = (const float*)d_in[1];
  const float* logridge = (const float*)d_in[2];
  float* out = (float*)d_out;

  const int n = in_sizes[0] / P;          // 20480 days
  const int W = n / STEPD - LAG_W;        // 1000 windows

  float* ws = (float*)d_ws;
  float* wbuf = ws;                        // 2*T_WIN + 1 floats
  float* e_all = ws + 1024;                // W floats
  float* s_all = ws + 1024 + W;            // W floats

  weights_kernel<<<1, 512, 0, stream>>>(a, wbuf);
  window_kernel<<<W, 256, 0, stream>>>(Y, wbuf, logridge, e_all, s_all, W);
  final_kernel<<<1, 256, 0, stream>>>(e_all, s_all, out, W);
}

// Round 4
// 651.557 us; speedup vs baseline: 1.3504x; 1.3504x over previous
//
#include <hip/hip_runtime.h>
#include <math.h>

#define P 128
#define T_WIN 480
#define STEPD 20
#define LAG_W 24

// ---------------- kernel 0: EWMA weights (fp64, one block) ----------------
// wbuf layout (floats): [0..479]=w_norm  [480..959]=sqrt(w_norm)  [960]=denom
// [961]=S (sum of raw a^e)  [962..985]=coef_m = a^(20*(23-m))  [986..1005]=bw_d = a^(19-d)
// [1006..1025 -> clipped to 1024) ... we store sqrt(bw_d) at [1000..1019]? NO:
// sqrt(bw_d) stored at [1006..1025] requires 1026 floats; wbuf region is 1024.
// -> store sqrt(bw_d) at [1004..1023] instead (20 floats, fits).
#define SBW_OFF 1004
__global__ __launch_bounds__(512) void weights_kernel(const float* __restrict__ a,
                                                      float* __restrict__ wbuf) {
  __shared__ double redd[512];
  const int t = threadIdx.x;
  const double la = log((double)a[0]);
  const double u = (t < T_WIN) ? exp((double)(T_WIN - 1 - t) * la) : 0.0;
  redd[t] = u;
  __syncthreads();
  for (int off = 256; off > 0; off >>= 1) {
    if (t < off) redd[t] += redd[t + off];
    __syncthreads();
  }
  const double S = redd[0];
  __syncthreads();
  redd[t] = u * u;
  __syncthreads();
  for (int off = 256; off > 0; off >>= 1) {
    if (t < off) redd[t] += redd[t + off];
    __syncthreads();
  }
  const double Su2 = redd[0];
  if (t < T_WIN) {
    const double wn = u / S * (double)T_WIN;
    wbuf[t] = (float)wn;
    wbuf[T_WIN + t] = (float)sqrt(wn);
  }
  if (t == 0) {
    wbuf[960] = (float)(1.0 - Su2 / (S * S));
    wbuf[961] = (float)S;
  }
  if (t < LAG_W) wbuf[962 + t] = (float)exp((double)(STEPD * (LAG_W - 1 - t)) * la);
  if (t < STEPD) {
    const double bw = exp((double)(STEPD - 1 - t) * la);
    wbuf[986 + t] = (float)bw;
    wbuf[SBW_OFF + t] = (float)sqrt(bw);   // sqrt(a^(19-d)) for syrk staging
  }
}

// ---------------- kernel 1: per-20-day-block outer products ----------------
// Stage rows scaled by sqrt(bw_d) so the outer product yields bw_d (NOT bw_d^2).
// C_k = sum_d bw_d y yT   (128x128), c_k = sum_d bw_d y   (128)
__global__ __launch_bounds__(256) void cblocks_kernel(const float* __restrict__ Y,
                                                      const float* __restrict__ wbuf,
                                                      float* __restrict__ cvec,
                                                      float* __restrict__ Call, int K) {
  const int k = blockIdx.x;
  const int tid = threadIdx.x;
  const int ti = tid >> 4, tj = tid & 15;
  __shared__ float st[STEPD][P];
  __shared__ float sbwsm[STEPD];
  if (tid < STEPD) sbwsm[tid] = wbuf[SBW_OFF + tid];
  __syncthreads();
  const float* __restrict__ Yb = Y + (size_t)k * STEPD * P;
  for (int i = tid; i < STEPD * P / 4; i += 256) {
    float4 v = ((const float4*)Yb)[i];
    const float sw = sbwsm[i >> 5];  // row = (i*4)>>7
    v.x *= sw; v.y *= sw; v.z *= sw; v.w *= sw;
    ((float4*)&st[0][0])[i] = v;
  }
  __syncthreads();

  float acc[8][8];
#pragma unroll
  for (int u = 0; u < 8; ++u)
#pragma unroll
    for (int v = 0; v < 8; ++v) acc[u][v] = 0.0f;

#pragma unroll 4
  for (int t = 0; t < STEPD; ++t) {
    float af[8], bf[8];
    *(float4*)(af)     = *(const float4*)&st[t][ti * 4];
    *(float4*)(af + 4) = *(const float4*)&st[t][64 + ti * 4];
    *(float4*)(bf)     = *(const float4*)&st[t][tj * 4];
    *(float4*)(bf + 4) = *(const float4*)&st[t][64 + tj * 4];
#pragma unroll
    for (int u = 0; u < 8; ++u)
#pragma unroll
      for (int v = 0; v < 8; ++v) acc[u][v] += af[u] * bf[v];
  }

  float* __restrict__ Ck = Call + (size_t)k * (P * P);
#pragma unroll
  for (int u = 0; u < 8; ++u) {
    const int r = (u < 4) ? (ti * 4 + u) : (64 + ti * 4 + u - 4);
    float4 o0, o1;
    o0.x = acc[u][0]; o0.y = acc[u][1]; o0.z = acc[u][2]; o0.w = acc[u][3];
    o1.x = acc[u][4]; o1.y = acc[u][5]; o1.z = acc[u][6]; o1.w = acc[u][7];
    *(float4*)(Ck + r * P + tj * 4) = o0;
    *(float4*)(Ck + r * P + 64 + tj * 4) = o1;
  }
  if (tid < P) {
    float s = 0.0f;
    for (int t = 0; t < STEPD; ++t) s += sbwsm[t] * st[t][tid];  // sqrt(bw)*sqrt(bw)*y = bw*y
    cvec[(size_t)k * P + tid] = s;
  }
}

// ---------------- kernel 2: one block per window ----------------
__global__ __launch_bounds__(256, 2) void window3_kernel(
    const float* __restrict__ Y, const float* __restrict__ wbuf,
    const float* __restrict__ logridge, const float* __restrict__ cvec,
    const float* __restrict__ Call, float* __restrict__ e_all,
    float* __restrict__ s_all, int W) {
  const int bid = blockIdx.x;
  int j;
  if ((W & 7) == 0) {            // bijective XCD swizzle
    const int q = W >> 3;
    j = (bid & 7) * q + (bid >> 3);
  } else {
    j = bid;
  }
  const int tid = threadIdx.x;
  const int ti = tid >> 4, tj = tid & 15;

  __shared__ float Msm[P][P + 1];   // 129 stride, scalar Cholesky-friendly
  __shared__ float dsm[P];          // sqrt'd diagonal kept separately
  __shared__ float meansm[P];
  __shared__ float coefsm[LAG_W];
  __shared__ float bsm[P];
  __shared__ float zsm[P];
  __shared__ float vsm[P];
  __shared__ float red[256];
  __shared__ float retd[STEPD];

  if (tid < LAG_W) coefsm[tid] = wbuf[962 + tid];
  if (tid < P) bsm[tid] = 1.0f;
  __syncthreads();

  const float S = wbuf[961];
  const float denom = wbuf[960];
  const float ridge = expf(logridge[0]);

  int rowi[8], rowoff[8];
#pragma unroll
  for (int u = 0; u < 8; ++u) {
    rowi[u] = (u < 4) ? (ti * 4 + u) : (64 + ti * 4 + u - 4);
    rowoff[u] = rowi[u] * P + tj * 4;
  }

  // ---- Araw = sum_m coef_m * C[j+m] ----
  float acc[8][8];
#pragma unroll
  for (int u = 0; u < 8; ++u)
#pragma unroll
    for (int v = 0; v < 8; ++v) acc[u][v] = 0.0f;

  for (int m = 0; m < LAG_W; ++m) {
    const float cf = coefsm[m];
    const float* __restrict__ Cm = Call + (size_t)(j + m) * (P * P);
#pragma unroll
    for (int u = 0; u < 8; ++u) {
      const float4 t0 = *(const float4*)(Cm + rowoff[u]);
      const float4 t1 = *(const float4*)(Cm + rowoff[u] + 64);
      acc[u][0] += cf * t0.x; acc[u][1] += cf * t0.y;
      acc[u][2] += cf * t0.z; acc[u][3] += cf * t0.w;
      acc[u][4] += cf * t1.x; acc[u][5] += cf * t1.y;
      acc[u][6] += cf * t1.z; acc[u][7] += cf * t1.w;
    }
  }

  // ---- mraw = sum_m coef_m * c[j+m] ----
  if (tid < P) {
    float s = 0.0f;
    for (int m = 0; m < LAG_W; ++m) s += coefsm[m] * cvec[(size_t)(j + m) * P + tid];
    meansm[tid] = s;
  }
  __syncthreads();

  // ---- M = Araw/(S*denom) - mraw mrawT/(S^2*denom) + ridge I ----
  {
    const float sc1 = 1.0f / (S * denom);
    const float sc2 = 1.0f / (S * S * denom);
#pragma unroll
    for (int u = 0; u < 8; ++u) {
      const int r = rowi[u];
      const float mr = meansm[r] * sc2;
#pragma unroll
      for (int v = 0; v < 8; ++v) {
        const int c = (v < 4) ? (tj * 4 + v) : (64 + tj * 4 + (v - 4));
        float mval = acc[u][v] * sc1 - mr * meansm[c];
        if (r == c) mval += ridge;
        Msm[r][c] = mval;
      }
    }
  }
  __syncthreads();

  // ---- Cholesky (lower, in place; full-square symmetric trailing update) ----
  for (int k = 0; k < P; ++k) {
    const float dkk = Msm[k][k];
    const float sq = sqrtf(dkk);
    const float invd = 1.0f / sq;
    if (tid == 0) dsm[k] = sq;
    const int i = k + 1 + tid;
    if (i < P) Msm[i][k] *= invd;
    __syncthreads();
    const int nrem = P - 1 - k;
    for (int ii = ti; ii < nrem; ii += 16) {
      const int ri = k + 1 + ii;
      const float Lik = Msm[ri][k];
      for (int jj = tj; jj < nrem; jj += 16) {
        const int cj = k + 1 + jj;
        Msm[ri][cj] -= Lik * Msm[cj][k];
      }
    }
    __syncthreads();
  }

  // ---- forward solve L z = 1 ----
  for (int k = 0; k < P; ++k) {
    const float zk = bsm[k] / dsm[k];
    if (tid == 0) zsm[k] = zk;
    const int i = k + 1 + tid;
    if (i < P) bsm[i] -= Msm[i][k] * zk;
    __syncthreads();
  }

  // ---- back solve L^T v = z ----
  for (int k = P - 1; k >= 0; --k) {
    const float vk = zsm[k] / dsm[k];
    if (tid == 0) vsm[k] = vk;
    if (tid < k) zsm[tid] -= Msm[k][tid] * vk;
    __syncthreads();
  }

  // ---- sum(v) ----
  red[tid] = (tid < P) ? vsm[tid] : 0.0f;
  __syncthreads();
  for (int off = 128; off > 0; off >>= 1) {
    if (tid < off) red[tid] += red[tid + off];
    __syncthreads();
  }

  // ---- test returns ----
  const float* __restrict__ Yte = Y + (size_t)(j + LAG_W) * STEPD * P;
  const int wv = tid >> 6;
  const int lane = tid & 63;
  for (int d = wv; d < STEPD; d += 4) {
    float pp = Yte[(size_t)d * P + lane] * vsm[lane] +
               Yte[(size_t)d * P + 64 + lane] * vsm[64 + lane];
    for (int off = 32; off > 0; off >>= 1) pp += __shfl_down(pp, off);
    if (lane == 0) retd[d] = pp;
  }
  __syncthreads();

  if (tid == 0) {
    const float invs = 1.0f / red[0];
    float e = 0.0f, s = 0.0f;
#pragma unroll
    for (int d = 0; d < STEPD; ++d) {
      const float r = retd[d] * invs;
      e += r;
      s += r * r;
    }
    e_all[j] = e;
    s_all[j] = s * (1.0f / (float)STEPD);
  }
}

// ---------------- fallback: R1 per-window kernel (used if ws too small) ----------------
__global__ __launch_bounds__(256, 2) void window_fallback(
    const float* __restrict__ Y, const float* __restrict__ wbuf,
    const float* __restrict__ logridge, float* __restrict__ e_all,
    float* __restrict__ s_all, int W) {
  const int j = blockIdx.x;
  const int tid = threadIdx.x;
  const int ti = tid >> 4;
  const int tj = tid & 15;

  __shared__ float Msm[P][P + 1];
  __shared__ float wsm[T_WIN];
  __shared__ float swsm[T_WIN];
  __shared__ float meansm[P];
  __shared__ float red[256];
  __shared__ float retd[STEPD];
  __shared__ float zsm[P];
  __shared__ float vsm[P];
  __shared__ float bsm[P];

  float* stage = &Msm[0][0];

  for (int t = tid; t < T_WIN; t += 256) {
    wsm[t] = wbuf[t];
    swsm[t] = wbuf[T_WIN + t];
  }
  if (tid < P) bsm[tid] = 1.0f;
  const float denom = wbuf[960];
  const float ridge = expf(logridge[0]);
  __syncthreads();

  const float* __restrict__ Ywin = Y + (size_t)j * STEPD * P;
  {
    const int col = tid & 127;
    const int half = tid >> 7;
    float m = 0.0f;
    const int t0 = half * (T_WIN / 2), t1 = t0 + T_WIN / 2;
    for (int t = t0; t < t1; ++t) m += wsm[t] * Ywin[(size_t)t * P + col];
    red[tid] = m;
    __syncthreads();
    if (tid < P) meansm[tid] = (red[tid] + red[tid + 128]) * (1.0f / (float)T_WIN);
    __syncthreads();
  }

  float acc[8][8];
#pragma unroll
  for (int u = 0; u < 8; ++u)
#pragma unroll
    for (int v = 0; v < 8; ++v) acc[u][v] = 0.0f;

  for (int c = 0; c < T_WIN / 32; ++c) {
    __syncthreads();
#pragma unroll
    for (int i = 0; i < 4; ++i) {
      const int idx = i * 1024 + tid * 4;
      float4 v = *(const float4*)(Ywin + (size_t)c * 32 * P + idx);
      const float sw = swsm[c * 32 + (idx >> 7)];
      v.x *= sw; v.y *= sw; v.z *= sw; v.w *= sw;
      *(float4*)(stage + idx) = v;
    }
    __syncthreads();
#pragma unroll 4
    for (int t = 0; t < 32; ++t) {
      const float* rowp = stage + t * P;
      float af[8], bf[8];
      *(float4*)(af) = *(const float4*)(rowp + ti * 8);
      *(float4*)(af + 4) = *(const float4*)(rowp + ti * 8 + 4);
      *(float4*)(bf) = *(const float4*)(rowp + tj * 8);
      *(float4*)(bf + 4) = *(const float4*)(rowp + tj * 8 + 4);
#pragma unroll
      for (int u = 0; u < 8; ++u)
#pragma unroll
        for (int v = 0; v < 8; ++v) acc[u][v] += af[u] * bf[v];
    }
  }
  __syncthreads();

  const float invTd = 1.0f / ((float)T_WIN * denom);
#pragma unroll
  for (int u = 0; u < 8; ++u) {
    const int r = ti * 8 + u;
    const float mr = meansm[r];
#pragma unroll
    for (int v = 0; v < 8; ++v) {
      const int cc = tj * 8 + v;
      float m = (acc[u][v] - (float)T_WIN * mr * meansm[cc]) * invTd;
      if (r == cc) m += ridge;
      Msm[r][cc] = m;
    }
  }
  __syncthreads();

  for (int k = 0; k < P; ++k) {
    const float dkk = Msm[k][k];
    const float sq = sqrtf(dkk);
    const float invd = 1.0f / sq;
    if (tid == 0) Msm[k][k] = sq;
    const int i = k + 1 + tid;
    if (i < P) Msm[i][k] *= invd;
    __syncthreads();
    const int nrem = P - 1 - k;
    for (int ii = ti; ii < nrem; ii += 16) {
      const int ri = k + 1 + ii;
      const float Lik = Msm[ri][k];
      for (int jj = tj; jj < nrem; jj += 16) {
        const int cj = k + 1 + jj;
        Msm[ri][cj] -= Lik * Msm[cj][k];
      }
    }
    __syncthreads();
  }

  for (int k = 0; k < P; ++k) {
    const float zk = bsm[k] / Msm[k][k];
    if (tid == 0) zsm[k] = zk;
    const int i = k + 1 + tid;
    if (i < P) bsm[i] -= Msm[i][k] * zk;
    __syncthreads();
  }
  for (int k = P - 1; k >= 0; --k) {
    const float vk = zsm[k] / Msm[k][k];
    if (tid == 0) vsm[k] = vk;
    if (tid < k) zsm[tid] -= Msm[k][tid] * vk;
    __syncthreads();
  }

  red[tid] = (tid < P) ? vsm[tid] : 0.0f;
  __syncthreads();
  for (int off = 128; off > 0; off >>= 1) {
    if (tid < off) red[tid] += red[tid + off];
    __syncthreads();
  }

  const float* __restrict__ Yte = Y + (size_t)(j + LAG_W) * STEPD * P;
  const int wv = tid >> 6;
  const int lane = tid & 63;
  for (int d = wv; d < STEPD; d += 4) {
    float pp = Yte[(size_t)d * P + lane] * vsm[lane] +
               Yte[(size_t)d * P + 64 + lane] * vsm[64 + lane];
    for (int off = 32; off > 0; off >>= 1) pp += __shfl_down(pp, off);
    if (lane == 0) retd[d] = pp;
  }
  __syncthreads();

  if (tid == 0) {
    const float invs = 1.0f / red[0];
    float e = 0.0f, s = 0.0f;
#pragma unroll
    for (int d = 0; d < STEPD; ++d) {
      const float r = retd[d] * invs;
      e += r;
      s += r * r;
    }
    e_all[j] = e;
    s_all[j] = s * (1.0f / (float)STEPD);
  }
}

// ---------------- kernel 3: final reduction ----------------
__global__ __launch_bounds__(256) void final_kernel(const float* __restrict__ e_all,
                                                    const float* __restrict__ s_all,
                                                    float* __restrict__ out, int W) {
  __shared__ float r1[256], r2[256];
  const int tid = threadIdx.x;
  float e = 0.0f, s = 0.0f;
  for (int i = tid; i < W; i += 256) {
    e += e_all[i];
    s += s_all[i];
  }
  r1[tid] = e;
  r2[tid] = s;
  __syncthreads();
  for (int off = 128; off > 0; off >>= 1) {
    if (tid < off) {
      r1[tid] += r1[tid + off];
      r2[tid] += r2[tid + off];
    }
    __syncthreads();
  }
  if (tid == 0) {
    const float vol = sqrtf(r2[0] / (float)W * 252.0f);
    const float mu = r1[0] / (float)W / (float)STEPD * 252.0f;
    out[0] = vol;
    out[1] = mu;
    out[2] = mu / vol;
  }
}

extern "C" void kernel_launch(void* const* d_in, const int* in_sizes, int n_in,
                              void* d_out, int out_size, void* d_ws, size_t ws_size,
                              hipStream_t stream) {
  const float* Y = (const float*)d_in[0];
  const float* a = (const float*)d_in[1];
  const float* logridge = (const float*)d_in[2];
  float* out = (float*)d_out;

  const int n = in_sizes[0] / P;     // 20480 days
  const int K = n / STEPD;           // 1024 blocks
  const int W = K - LAG_W;           // 1000 windows

  float* ws = (float*)d_ws;
  float* wbuf = ws;                  // 1024 floats
  float* e_all = ws + 1024;          // W
  float* s_all = ws + 2048;          // W
  float* cvec = ws + 4096;           // K*128
  float* Call = ws + 4096 + (size_t)K * P;  // K*128*128

  const size_t need = ((size_t)4096 + (size_t)K * P + (size_t)K * P * P) * sizeof(float);

  weights_kernel<<<1, 512, 0, stream>>>(a, wbuf);
  if (ws_size >= need && (n % STEPD) == 0 && W > 0 && W <= 1024) {
    cblocks_kernel<<<K, 256, 0, stream>>>(Y, wbuf, cvec, Call, K);
    window3_kernel<<<W, 256, 0, stream>>>(Y, wbuf, logridge, cvec, Call, e_all, s_all, W);
  } else {
    window_fallback<<<W, 256, 0, stream>>>(Y, wbuf, logridge, e_all, s_all, W);
  }
  final_kernel<<<1, 256, 0, stream>>>(e_all, s_all, out, W);
}

// Round 5
// 277.128 us; speedup vs baseline: 3.1748x; 2.3511x over previous
//
#include <hip/hip_runtime.h>
#include <math.h>

#define P 128
#define T_WIN 480
#define STEPD 20
#define LAG_W 24
#define NITER 32

// ---------------- kernel 0: EWMA weights (fp64, one block) ----------------
// wbuf layout (floats): [0..479]=w_norm  [480..959]=sqrt(w_norm)  [960]=denom
// [961]=S  [962..985]=coef_m = a^(20*(23-m))  [986..1005]=bw_d = a^(19-d)
// [1004..1023]=sqrt(bw_d)
#define SBW_OFF 1004
__global__ __launch_bounds__(512) void weights_kernel(const float* __restrict__ a,
                                                      float* __restrict__ wbuf) {
  __shared__ double redd[512];
  const int t = threadIdx.x;
  const double la = log((double)a[0]);
  const double u = (t < T_WIN) ? exp((double)(T_WIN - 1 - t) * la) : 0.0;
  redd[t] = u;
  __syncthreads();
  for (int off = 256; off > 0; off >>= 1) {
    if (t < off) redd[t] += redd[t + off];
    __syncthreads();
  }
  const double S = redd[0];
  __syncthreads();
  redd[t] = u * u;
  __syncthreads();
  for (int off = 256; off > 0; off >>= 1) {
    if (t < off) redd[t] += redd[t + off];
    __syncthreads();
  }
  const double Su2 = redd[0];
  if (t < T_WIN) {
    const double wn = u / S * (double)T_WIN;
    wbuf[t] = (float)wn;
    wbuf[T_WIN + t] = (float)sqrt(wn);
  }
  if (t == 0) {
    wbuf[960] = (float)(1.0 - Su2 / (S * S));
    wbuf[961] = (float)S;
  }
  if (t < LAG_W) wbuf[962 + t] = (float)exp((double)(STEPD * (LAG_W - 1 - t)) * la);
  if (t < STEPD) {
    const double bw = exp((double)(STEPD - 1 - t) * la);
    wbuf[986 + t] = (float)bw;
    wbuf[SBW_OFF + t] = (float)sqrt(bw);
  }
}

// ---------------- kernel 1: per-20-day-block outer products ----------------
// C_k = sum_d bw_d y yT, c_k = sum_d bw_d y  (rows staged scaled by sqrt(bw_d))
__global__ __launch_bounds__(256) void cblocks_kernel(const float* __restrict__ Y,
                                                      const float* __restrict__ wbuf,
                                                      float* __restrict__ cvec,
                                                      float* __restrict__ Call, int K) {
  const int k = blockIdx.x;
  const int tid = threadIdx.x;
  const int ti = tid >> 4, tj = tid & 15;
  __shared__ float st[STEPD][P];
  __shared__ float sbwsm[STEPD];
  if (tid < STEPD) sbwsm[tid] = wbuf[SBW_OFF + tid];
  __syncthreads();
  const float* __restrict__ Yb = Y + (size_t)k * STEPD * P;
  for (int i = tid; i < STEPD * P / 4; i += 256) {
    float4 v = ((const float4*)Yb)[i];
    const float sw = sbwsm[i >> 5];
    v.x *= sw; v.y *= sw; v.z *= sw; v.w *= sw;
    ((float4*)&st[0][0])[i] = v;
  }
  __syncthreads();

  float acc[8][8];
#pragma unroll
  for (int u = 0; u < 8; ++u)
#pragma unroll
    for (int v = 0; v < 8; ++v) acc[u][v] = 0.0f;

#pragma unroll 4
  for (int t = 0; t < STEPD; ++t) {
    float af[8], bf[8];
    *(float4*)(af)     = *(const float4*)&st[t][ti * 4];
    *(float4*)(af + 4) = *(const float4*)&st[t][64 + ti * 4];
    *(float4*)(bf)     = *(const float4*)&st[t][tj * 4];
    *(float4*)(bf + 4) = *(const float4*)&st[t][64 + tj * 4];
#pragma unroll
    for (int u = 0; u < 8; ++u)
#pragma unroll
      for (int v = 0; v < 8; ++v) acc[u][v] += af[u] * bf[v];
  }

  float* __restrict__ Ck = Call + (size_t)k * (P * P);
#pragma unroll
  for (int u = 0; u < 8; ++u) {
    const int r = (u < 4) ? (ti * 4 + u) : (64 + ti * 4 + u - 4);
    float4 o0, o1;
    o0.x = acc[u][0]; o0.y = acc[u][1]; o0.z = acc[u][2]; o0.w = acc[u][3];
    o1.x = acc[u][4]; o1.y = acc[u][5]; o1.z = acc[u][6]; o1.w = acc[u][7];
    *(float4*)(Ck + r * P + tj * 4) = o0;
    *(float4*)(Ck + r * P + 64 + tj * 4) = o1;
  }
  if (tid < P) {
    float s = 0.0f;
    for (int t = 0; t < STEPD; ++t) s += sbwsm[t] * st[t][tid];
    cvec[(size_t)k * P + tid] = s;
  }
}

// ---------------- kernel 2: one block per window; CG solve in registers ----------------
__global__ __launch_bounds__(256, 4) void window4_kernel(
    const float* __restrict__ Y, const float* __restrict__ wbuf,
    const float* __restrict__ logridge, const float* __restrict__ cvec,
    const float* __restrict__ Call, float* __restrict__ e_all,
    float* __restrict__ s_all, int W) {
  const int bid = blockIdx.x;
  int j;
  if ((W & 7) == 0) {            // bijective XCD swizzle
    const int q = W >> 3;
    j = (bid & 7) * q + (bid >> 3);
  } else {
    j = bid;
  }
  const int tid = threadIdx.x;
  const int ti = tid >> 4, tj = tid & 15;
  const int lane = tid & 63;
  const int wv = tid >> 6;

  __shared__ float psm[P];
  __shared__ float Apsm[P];
  __shared__ float vsm[P];
  __shared__ float meansm[P];
  __shared__ float coefsm[LAG_W];
  __shared__ float pap_wave[4];
  __shared__ float rs_wave[4];
  __shared__ float retd[STEPD];

  if (tid < LAG_W) coefsm[tid] = wbuf[962 + tid];
  __syncthreads();

  const float S = wbuf[961];
  const float denom = wbuf[960];
  const float ridge = expf(logridge[0]);

  int rowi[8], rowoff[8];
#pragma unroll
  for (int u = 0; u < 8; ++u) {
    rowi[u] = (u < 4) ? (ti * 4 + u) : (64 + ti * 4 + u - 4);
    rowoff[u] = rowi[u] * P + tj * 4;
  }

  // ---- Araw = sum_m coef_m * C[j+m]  (accumulated in registers) ----
  float acc[8][8];
#pragma unroll
  for (int u = 0; u < 8; ++u)
#pragma unroll
    for (int v = 0; v < 8; ++v) acc[u][v] = 0.0f;

  for (int m = 0; m < LAG_W; ++m) {
    const float cf = coefsm[m];
    const float* __restrict__ Cm = Call + (size_t)(j + m) * (P * P);
#pragma unroll
    for (int u = 0; u < 8; ++u) {
      const float4 t0 = *(const float4*)(Cm + rowoff[u]);
      const float4 t1 = *(const float4*)(Cm + rowoff[u] + 64);
      acc[u][0] += cf * t0.x; acc[u][1] += cf * t0.y;
      acc[u][2] += cf * t0.z; acc[u][3] += cf * t0.w;
      acc[u][4] += cf * t1.x; acc[u][5] += cf * t1.y;
      acc[u][6] += cf * t1.z; acc[u][7] += cf * t1.w;
    }
  }

  // ---- mraw = sum_m coef_m * c[j+m] ----
  if (tid < P) {
    float s = 0.0f;
    for (int m = 0; m < LAG_W; ++m) s += coefsm[m] * cvec[(size_t)(j + m) * P + tid];
    meansm[tid] = s;
  }
  __syncthreads();

  // ---- M (in registers) = Araw/(S*denom) - mraw mrawT/(S^2*denom) + ridge I ----
  {
    const float sc1 = 1.0f / (S * denom);
    const float sc2 = 1.0f / (S * S * denom);
#pragma unroll
    for (int u = 0; u < 8; ++u) {
      const int r = rowi[u];
      const float mr = meansm[r] * sc2;
#pragma unroll
      for (int v = 0; v < 8; ++v) {
        const int c = (v < 4) ? (tj * 4 + v) : (64 + tj * 4 + (v - 4));
        float mval = acc[u][v] * sc1 - mr * meansm[c];
        if (r == c) mval += ridge;
        acc[u][v] = mval;
      }
    }
  }

  // ---- CG solve M v = 1 ; x,r,p component `tid` owned by threads tid<128 ----
  float xo = 0.0f, ro = 1.0f, po = 1.0f;
  float rs_old = (float)P;
  if (tid < P) psm[tid] = 1.0f;
  __syncthreads();

  for (int it = 0; it < NITER; ++it) {
    // matvec: Ap = M p (register tile x LDS vector, butterfly row-reduce)
    const float4 p0 = *(const float4*)&psm[tj * 4];
    const float4 p1 = *(const float4*)&psm[64 + tj * 4];
    float pv[8] = {p0.x, p0.y, p0.z, p0.w, p1.x, p1.y, p1.z, p1.w};
    float ap[8];
#pragma unroll
    for (int u = 0; u < 8; ++u) {
      float s = 0.0f;
#pragma unroll
      for (int v = 0; v < 8; ++v) s += acc[u][v] * pv[v];
      ap[u] = s;
    }
#pragma unroll
    for (int m = 1; m <= 8; m <<= 1) {
#pragma unroll
      for (int u = 0; u < 8; ++u) ap[u] += __shfl_xor(ap[u], m);
    }
    if (tj == 0) {
      float papp = 0.0f;
#pragma unroll
      for (int u = 0; u < 8; ++u) {
        Apsm[rowi[u]] = ap[u];
        papp += ap[u] * psm[rowi[u]];
      }
      papp += __shfl_down(papp, 16);
      papp += __shfl_down(papp, 32);
      if (lane == 0) pap_wave[wv] = papp;
    }
    __syncthreads();  // B1

    const float pap = pap_wave[0] + pap_wave[1] + pap_wave[2] + pap_wave[3];
    const float alpha = rs_old / pap;
    float rsp = 0.0f;
    if (tid < P) {
      xo += alpha * po;
      ro -= alpha * Apsm[tid];
      rsp = ro * ro;
    }
#pragma unroll
    for (int m = 32; m > 0; m >>= 1) rsp += __shfl_down(rsp, m);
    if (lane == 0) rs_wave[wv] = rsp;
    __syncthreads();  // B2

    const float rs_new = rs_wave[0] + rs_wave[1] + rs_wave[2] + rs_wave[3];
    const float beta = rs_new / rs_old;
    rs_old = rs_new;
    if (tid < P) {
      po = ro + beta * po;
      psm[tid] = po;
    }
    __syncthreads();  // B3
  }

  // ---- v = xo ; sum(v) ----
  if (tid < P) vsm[tid] = xo;
  float sv = (tid < P) ? xo : 0.0f;
#pragma unroll
  for (int m = 32; m > 0; m >>= 1) sv += __shfl_down(sv, m);
  if (lane == 0) rs_wave[wv] = sv;
  __syncthreads();
  const float sumv = rs_wave[0] + rs_wave[1] + rs_wave[2] + rs_wave[3];

  // ---- test returns ----
  const float* __restrict__ Yte = Y + (size_t)(j + LAG_W) * STEPD * P;
  for (int d = wv; d < STEPD; d += 4) {
    float pp = Yte[(size_t)d * P + lane] * vsm[lane] +
               Yte[(size_t)d * P + 64 + lane] * vsm[64 + lane];
    for (int off = 32; off > 0; off >>= 1) pp += __shfl_down(pp, off);
    if (lane == 0) retd[d] = pp;
  }
  __syncthreads();

  if (tid == 0) {
    const float invs = 1.0f / sumv;
    float e = 0.0f, s = 0.0f;
#pragma unroll
    for (int d = 0; d < STEPD; ++d) {
      const float r = retd[d] * invs;
      e += r;
      s += r * r;
    }
    e_all[j] = e;
    s_all[j] = s * (1.0f / (float)STEPD);
  }
}

// ---------------- fallback: R1 per-window kernel (used if ws too small) ----------------
__global__ __launch_bounds__(256, 2) void window_fallback(
    const float* __restrict__ Y, const float* __restrict__ wbuf,
    const float* __restrict__ logridge, float* __restrict__ e_all,
    float* __restrict__ s_all, int W) {
  const int j = blockIdx.x;
  const int tid = threadIdx.x;
  const int ti = tid >> 4;
  const int tj = tid & 15;

  __shared__ float Msm[P][P + 1];
  __shared__ float wsm[T_WIN];
  __shared__ float swsm[T_WIN];
  __shared__ float meansm[P];
  __shared__ float red[256];
  __shared__ float retd[STEPD];
  __shared__ float zsm[P];
  __shared__ float vsm[P];
  __shared__ float bsm[P];

  float* stage = &Msm[0][0];

  for (int t = tid; t < T_WIN; t += 256) {
    wsm[t] = wbuf[t];
    swsm[t] = wbuf[T_WIN + t];
  }
  if (tid < P) bsm[tid] = 1.0f;
  const float denom = wbuf[960];
  const float ridge = expf(logridge[0]);
  __syncthreads();

  const float* __restrict__ Ywin = Y + (size_t)j * STEPD * P;
  {
    const int col = tid & 127;
    const int half = tid >> 7;
    float m = 0.0f;
    const int t0 = half * (T_WIN / 2), t1 = t0 + T_WIN / 2;
    for (int t = t0; t < t1; ++t) m += wsm[t] * Ywin[(size_t)t * P + col];
    red[tid] = m;
    __syncthreads();
    if (tid < P) meansm[tid] = (red[tid] + red[tid + 128]) * (1.0f / (float)T_WIN);
    __syncthreads();
  }

  float acc[8][8];
#pragma unroll
  for (int u = 0; u < 8; ++u)
#pragma unroll
    for (int v = 0; v < 8; ++v) acc[u][v] = 0.0f;

  for (int c = 0; c < T_WIN / 32; ++c) {
    __syncthreads();
#pragma unroll
    for (int i = 0; i < 4; ++i) {
      const int idx = i * 1024 + tid * 4;
      float4 v = *(const float4*)(Ywin + (size_t)c * 32 * P + idx);
      const float sw = swsm[c * 32 + (idx >> 7)];
      v.x *= sw; v.y *= sw; v.z *= sw; v.w *= sw;
      *(float4*)(stage + idx) = v;
    }
    __syncthreads();
#pragma unroll 4
    for (int t = 0; t < 32; ++t) {
      const float* rowp = stage + t * P;
      float af[8], bf[8];
      *(float4*)(af) = *(const float4*)(rowp + ti * 8);
      *(float4*)(af + 4) = *(const float4*)(rowp + ti * 8 + 4);
      *(float4*)(bf) = *(const float4*)(rowp + tj * 8);
      *(float4*)(bf + 4) = *(const float4*)(rowp + tj * 8 + 4);
#pragma unroll
      for (int u = 0; u < 8; ++u)
#pragma unroll
        for (int v = 0; v < 8; ++v) acc[u][v] += af[u] * bf[v];
    }
  }
  __syncthreads();

  const float invTd = 1.0f / ((float)T_WIN * denom);
#pragma unroll
  for (int u = 0; u < 8; ++u) {
    const int r = ti * 8 + u;
    const float mr = meansm[r];
#pragma unroll
    for (int v = 0; v < 8; ++v) {
      const int cc = tj * 8 + v;
      float m = (acc[u][v] - (float)T_WIN * mr * meansm[cc]) * invTd;
      if (r == cc) m += ridge;
      Msm[r][cc] = m;
    }
  }
  __syncthreads();

  for (int k = 0; k < P; ++k) {
    const float dkk = Msm[k][k];
    const float sq = sqrtf(dkk);
    const float invd = 1.0f / sq;
    if (tid == 0) Msm[k][k] = sq;
    const int i = k + 1 + tid;
    if (i < P) Msm[i][k] *= invd;
    __syncthreads();
    const int nrem = P - 1 - k;
    for (int ii = ti; ii < nrem; ii += 16) {
      const int ri = k + 1 + ii;
      const float Lik = Msm[ri][k];
      for (int jj = tj; jj < nrem; jj += 16) {
        const int cj = k + 1 + jj;
        Msm[ri][cj] -= Lik * Msm[cj][k];
      }
    }
    __syncthreads();
  }

  for (int k = 0; k < P; ++k) {
    const float zk = bsm[k] / Msm[k][k];
    if (tid == 0) zsm[k] = zk;
    const int i = k + 1 + tid;
    if (i < P) bsm[i] -= Msm[i][k] * zk;
    __syncthreads();
  }
  for (int k = P - 1; k >= 0; --k) {
    const float vk = zsm[k] / Msm[k][k];
    if (tid == 0) vsm[k] = vk;
    if (tid < k) zsm[tid] -= Msm[k][tid] * vk;
    __syncthreads();
  }

  red[tid] = (tid < P) ? vsm[tid] : 0.0f;
  __syncthreads();
  for (int off = 128; off > 0; off >>= 1) {
    if (tid < off) red[tid] += red[tid + off];
    __syncthreads();
  }

  const float* __restrict__ Yte = Y + (size_t)(j + LAG_W) * STEPD * P;
  const int wv = tid >> 6;
  const int lane = tid & 63;
  for (int d = wv; d < STEPD; d += 4) {
    float pp = Yte[(size_t)d * P + lane] * vsm[lane] +
               Yte[(size_t)d * P + 64 + lane] * vsm[64 + lane];
    for (int off = 32; off > 0; off >>= 1) pp += __shfl_down(pp, off);
    if (lane == 0) retd[d] = pp;
  }
  __syncthreads();

  if (tid == 0) {
    const float invs = 1.0f / red[0];
    float e = 0.0f, s = 0.0f;
#pragma unroll
    for (int d = 0; d < STEPD; ++d) {
      const float r = retd[d] * invs;
      e += r;
      s += r * r;
    }
    e_all[j] = e;
    s_all[j] = s * (1.0f / (float)STEPD);
  }
}

// ---------------- kernel 3: final reduction ----------------
__global__ __launch_bounds__(256) void final_kernel(const float* __restrict__ e_all,
                                                    const float* __restrict__ s_all,
                                                    float* __restrict__ out, int W) {
  __shared__ float r1[256], r2[256];
  const int tid = threadIdx.x;
  float e = 0.0f, s = 0.0f;
  for (int i = tid; i < W; i += 256) {
    e += e_all[i];
    s += s_all[i];
  }
  r1[tid] = e;
  r2[tid] = s;
  __syncthreads();
  for (int off = 128; off > 0; off >>= 1) {
    if (tid < off) {
      r1[tid] += r1[tid + off];
      r2[tid] += r2[tid + off];
    }
    __syncthreads();
  }
  if (tid == 0) {
    const float vol = sqrtf(r2[0] / (float)W * 252.0f);
    const float mu = r1[0] / (float)W / (float)STEPD * 252.0f;
    out[0] = vol;
    out[1] = mu;
    out[2] = mu / vol;
  }
}

extern "C" void kernel_launch(void* const* d_in, const int* in_sizes, int n_in,
                              void* d_out, int out_size, void* d_ws, size_t ws_size,
                              hipStream_t stream) {
  const float* Y = (const float*)d_in[0];
  const float* a = (const float*)d_in[1];
  const float* logridge = (const float*)d_in[2];
  float* out = (float*)d_out;

  const int n = in_sizes[0] / P;     // 20480 days
  const int K = n / STEPD;           // 1024 blocks
  const int W = K - LAG_W;           // 1000 windows

  float* ws = (float*)d_ws;
  float* wbuf = ws;                  // 1024 floats
  float* e_all = ws + 1024;          // W
  float* s_all = ws + 2048;          // W
  float* cvec = ws + 4096;           // K*128
  float* Call = ws + 4096 + (size_t)K * P;  // K*128*128

  const size_t need = ((size_t)4096 + (size_t)K * P + (size_t)K * P * P) * sizeof(float);

  weights_kernel<<<1, 512, 0, stream>>>(a, wbuf);
  if (ws_size >= need && (n % STEPD) == 0 && W > 0 && W <= 1024) {
    cblocks_kernel<<<K, 256, 0, stream>>>(Y, wbuf, cvec, Call, K);
    window4_kernel<<<W, 256, 0, stream>>>(Y, wbuf, logridge, cvec, Call, e_all, s_all, W);
  } else {
    window_fallback<<<W, 256, 0, stream>>>(Y, wbuf, logridge, e_all, s_all, W);
  }
  final_kernel<<<1, 256, 0, stream>>>(e_all, s_all, out, W);
}

// Round 6
// 159.314 us; speedup vs baseline: 5.5226x; 1.7395x over previous
//
#include <hip/hip_runtime.h>
#include <math.h>

#define P 128
#define T_WIN 480
#define STEPD 20
#define LAG_W 24
#define NITER 32
#define SEG 128

// wbuf layout (floats, 2048 total):
// [0..479]=w_norm  [480..959]=sqrt(w_norm)  [960]=denom  [961]=S
// [962..985]=coef_m=a^(20(23-m))  [986..1005]=sqrt(bw_d)=sqrt(a^(19-d))
// [1024..1174]=pw20[x]=a^(20x), x=0..150   [1280..1407]=ainvt[k]=a^(-20k), k=0..127
#define SBW_OFF 986
#define PW20_OFF 1024
#define AINVT_OFF 1280

// ---------------- kernel 0: EWMA weights (fp64, one block) ----------------
__global__ __launch_bounds__(512) void weights_kernel(const float* __restrict__ a,
                                                      float* __restrict__ wbuf) {
  __shared__ double redd[512];
  const int t = threadIdx.x;
  const double la = log((double)a[0]);
  const double u = (t < T_WIN) ? exp((double)(T_WIN - 1 - t) * la) : 0.0;
  redd[t] = u;
  __syncthreads();
  for (int off = 256; off > 0; off >>= 1) {
    if (t < off) redd[t] += redd[t + off];
    __syncthreads();
  }
  const double S = redd[0];
  __syncthreads();
  redd[t] = u * u;
  __syncthreads();
  for (int off = 256; off > 0; off >>= 1) {
    if (t < off) redd[t] += redd[t + off];
    __syncthreads();
  }
  const double Su2 = redd[0];
  if (t < T_WIN) {
    const double wn = u / S * (double)T_WIN;
    wbuf[t] = (float)wn;
    wbuf[T_WIN + t] = (float)sqrt(wn);
  }
  if (t == 0) {
    wbuf[960] = (float)(1.0 - Su2 / (S * S));
    wbuf[961] = (float)S;
  }
  if (t < LAG_W) wbuf[962 + t] = (float)exp((double)(STEPD * (LAG_W - 1 - t)) * la);
  if (t < STEPD) wbuf[SBW_OFF + t] = (float)exp(0.5 * (double)(STEPD - 1 - t) * la);
  if (t < 151) wbuf[PW20_OFF + t] = (float)exp((double)(20 * t) * la);
  if (t < SEG) wbuf[AINVT_OFF + t] = (float)exp(-(double)(20 * t) * la);
}

// ---------------- kernel 1: per-20-day-block outer products ----------------
// C_k = sum_d bw_d y yT, c_k = sum_d bw_d y  (rows staged scaled by sqrt(bw_d))
__global__ __launch_bounds__(256) void cblocks_kernel(const float* __restrict__ Y,
                                                      const float* __restrict__ wbuf,
                                                      float* __restrict__ cvec,
                                                      float* __restrict__ Call, int K) {
  const int k = blockIdx.x;
  const int tid = threadIdx.x;
  const int ti = tid >> 4, tj = tid & 15;
  __shared__ float st[STEPD][P];
  __shared__ float sbwsm[STEPD];
  if (tid < STEPD) sbwsm[tid] = wbuf[SBW_OFF + tid];
  __syncthreads();
  const float* __restrict__ Yb = Y + (size_t)k * STEPD * P;
  for (int i = tid; i < STEPD * P / 4; i += 256) {
    float4 v = ((const float4*)Yb)[i];
    const float sw = sbwsm[i >> 5];
    v.x *= sw; v.y *= sw; v.z *= sw; v.w *= sw;
    ((float4*)&st[0][0])[i] = v;
  }
  __syncthreads();

  float acc[8][8];
#pragma unroll
  for (int u = 0; u < 8; ++u)
#pragma unroll
    for (int v = 0; v < 8; ++v) acc[u][v] = 0.0f;

#pragma unroll 4
  for (int t = 0; t < STEPD; ++t) {
    float af[8], bf[8];
    *(float4*)(af)     = *(const float4*)&st[t][ti * 4];
    *(float4*)(af + 4) = *(const float4*)&st[t][64 + ti * 4];
    *(float4*)(bf)     = *(const float4*)&st[t][tj * 4];
    *(float4*)(bf + 4) = *(const float4*)&st[t][64 + tj * 4];
#pragma unroll
    for (int u = 0; u < 8; ++u)
#pragma unroll
      for (int v = 0; v < 8; ++v) acc[u][v] += af[u] * bf[v];
  }

  float* __restrict__ Ck = Call + (size_t)k * (P * P);
#pragma unroll
  for (int u = 0; u < 8; ++u) {
    const int r = (u < 4) ? (ti * 4 + u) : (64 + ti * 4 + u - 4);
    float4 o0, o1;
    o0.x = acc[u][0]; o0.y = acc[u][1]; o0.z = acc[u][2]; o0.w = acc[u][3];
    o1.x = acc[u][4]; o1.y = acc[u][5]; o1.z = acc[u][6]; o1.w = acc[u][7];
    *(float4*)(Ck + r * P + tj * 4) = o0;
    *(float4*)(Ck + r * P + 64 + tj * 4) = o1;
  }
  if (tid < P) {
    float s = 0.0f;
    for (int t = 0; t < STEPD; ++t) s += sbwsm[t] * st[t][tid];
    cvec[(size_t)k * P + tid] = s;
  }
}

// ---------------- kernel 1.5: segmented weighted prefix scan (in place) ----------------
// G[k] = sum_{i=o_s}^{k} a^(-20(i-o_s)) C_i  for k in segment s (o_s = s*SEG)
// grid: (K/SEG) * 64 blocks of 256; each thread scans one of 16384 elements.
__global__ __launch_bounds__(256) void scan_kernel(float* __restrict__ Call,
                                                   const float* __restrict__ wbuf) {
  __shared__ float asm_[SEG];
  const int tid = threadIdx.x;
  const int seg = blockIdx.x >> 6;
  const int chunk = blockIdx.x & 63;
  if (tid < SEG) asm_[tid] = wbuf[AINVT_OFF + tid];
  __syncthreads();
  const int e = chunk * 256 + tid;
  float* __restrict__ base = Call + ((size_t)seg * SEG) * (P * P) + e;
  float g = 0.0f;
#pragma unroll 4
  for (int k = 0; k < SEG; ++k) {
    const float c = base[(size_t)k * (P * P)];
    g = fmaf(asm_[k], c, g);
    base[(size_t)k * (P * P)] = g;
  }
}

// ---------------- kernel 2: one block per window; Araw from G-differences; CG solve ----------------
__global__ __launch_bounds__(256, 4) void window5_kernel(
    const float* __restrict__ Y, const float* __restrict__ wbuf,
    const float* __restrict__ logridge, const float* __restrict__ cvec,
    const float* __restrict__ Gall, float* __restrict__ e_all,
    float* __restrict__ s_all, int W) {
  const int bid = blockIdx.x;
  int j;
  if ((W & 7) == 0) {            // bijective XCD swizzle
    const int q = W >> 3;
    j = (bid & 7) * q + (bid >> 3);
  } else {
    j = bid;
  }
  const int tid = threadIdx.x;
  const int ti = tid >> 4, tj = tid & 15;
  const int lane = tid & 63;
  const int wv = tid >> 6;

  __shared__ float psm[P];
  __shared__ float Apsm[P];
  __shared__ float vsm[P];
  __shared__ float meansm[P];
  __shared__ float coefsm[LAG_W];
  __shared__ float pap_wave[4];
  __shared__ float rs_wave[4];
  __shared__ float retd[STEPD];

  if (tid < LAG_W) coefsm[tid] = wbuf[962 + tid];
  __syncthreads();

  const float S = wbuf[961];
  const float denom = wbuf[960];
  const float ridge = expf(logridge[0]);

  int rowi[8], rowoff[8];
#pragma unroll
  for (int u = 0; u < 8; ++u) {
    rowi[u] = (u < 4) ? (ti * 4 + u) : (64 + ti * 4 + u - 4);
    rowoff[u] = rowi[u] * P + tj * 4;
  }

  // ---- Araw = sum_k a^(20(j+23-k)) C_k  via segmented prefix differences ----
  const int o1 = j & ~(SEG - 1);
  const int end = j + 23;
  const int b = o1 + SEG;
  int mats[3];
  float scls[3];
  int nm = 0;
  {
    const float pA = wbuf[PW20_OFF + (end - o1)];
    if (end < b) {
      mats[nm] = end; scls[nm] = pA; ++nm;
      if (j > o1) { mats[nm] = j - 1; scls[nm] = -pA; ++nm; }
    } else {
      const float pB = wbuf[PW20_OFF + (end - b)];
      mats[nm] = b - 1; scls[nm] = pA; ++nm;
      if (j > o1) { mats[nm] = j - 1; scls[nm] = -pA; ++nm; }
      mats[nm] = end; scls[nm] = pB; ++nm;
    }
  }

  float acc[8][8];
#pragma unroll
  for (int u = 0; u < 8; ++u)
#pragma unroll
    for (int v = 0; v < 8; ++v) acc[u][v] = 0.0f;

  for (int m = 0; m < nm; ++m) {
    const float cf = scls[m];
    const float* __restrict__ Gm = Gall + (size_t)mats[m] * (P * P);
#pragma unroll
    for (int u = 0; u < 8; ++u) {
      const float4 t0 = *(const float4*)(Gm + rowoff[u]);
      const float4 t1 = *(const float4*)(Gm + rowoff[u] + 64);
      acc[u][0] += cf * t0.x; acc[u][1] += cf * t0.y;
      acc[u][2] += cf * t0.z; acc[u][3] += cf * t0.w;
      acc[u][4] += cf * t1.x; acc[u][5] += cf * t1.y;
      acc[u][6] += cf * t1.z; acc[u][7] += cf * t1.w;
    }
  }

  // ---- mraw = sum_m coef_m * c[j+m] ----
  if (tid < P) {
    float s = 0.0f;
    for (int m = 0; m < LAG_W; ++m) s += coefsm[m] * cvec[(size_t)(j + m) * P + tid];
    meansm[tid] = s;
  }
  __syncthreads();

  // ---- M (in registers) = Araw/(S*denom) - mraw mrawT/(S^2*denom) + ridge I ----
  {
    const float sc1 = 1.0f / (S * denom);
    const float sc2 = 1.0f / (S * S * denom);
#pragma unroll
    for (int u = 0; u < 8; ++u) {
      const int r = rowi[u];
      const float mr = meansm[r] * sc2;
#pragma unroll
      for (int v = 0; v < 8; ++v) {
        const int c = (v < 4) ? (tj * 4 + v) : (64 + tj * 4 + (v - 4));
        float mval = acc[u][v] * sc1 - mr * meansm[c];
        if (r == c) mval += ridge;
        acc[u][v] = mval;
      }
    }
  }

  // ---- CG solve M v = 1 ----
  float xo = 0.0f, ro = 1.0f, po = 1.0f;
  float rs_old = (float)P;
  if (tid < P) psm[tid] = 1.0f;
  __syncthreads();

  for (int it = 0; it < NITER; ++it) {
    const float4 p0 = *(const float4*)&psm[tj * 4];
    const float4 p1 = *(const float4*)&psm[64 + tj * 4];
    float pv[8] = {p0.x, p0.y, p0.z, p0.w, p1.x, p1.y, p1.z, p1.w};
    float ap[8];
#pragma unroll
    for (int u = 0; u < 8; ++u) {
      float s = 0.0f;
#pragma unroll
      for (int v = 0; v < 8; ++v) s += acc[u][v] * pv[v];
      ap[u] = s;
    }
#pragma unroll
    for (int m = 1; m <= 8; m <<= 1) {
#pragma unroll
      for (int u = 0; u < 8; ++u) ap[u] += __shfl_xor(ap[u], m);
    }
    if (tj == 0) {
      float papp = 0.0f;
#pragma unroll
      for (int u = 0; u < 8; ++u) {
        Apsm[rowi[u]] = ap[u];
        papp += ap[u] * psm[rowi[u]];
      }
      papp += __shfl_down(papp, 16);
      papp += __shfl_down(papp, 32);
      if (lane == 0) pap_wave[wv] = papp;
    }
    __syncthreads();  // B1

    const float pap = pap_wave[0] + pap_wave[1] + pap_wave[2] + pap_wave[3];
    const float alpha = rs_old / pap;
    float rsp = 0.0f;
    if (tid < P) {
      xo += alpha * po;
      ro -= alpha * Apsm[tid];
      rsp = ro * ro;
    }
#pragma unroll
    for (int m = 32; m > 0; m >>= 1) rsp += __shfl_down(rsp, m);
    if (lane == 0) rs_wave[wv] = rsp;
    __syncthreads();  // B2

    const float rs_new = rs_wave[0] + rs_wave[1] + rs_wave[2] + rs_wave[3];
    const float beta = rs_new / rs_old;
    rs_old = rs_new;
    if (tid < P) {
      po = ro + beta * po;
      psm[tid] = po;
    }
    __syncthreads();  // B3
  }

  // ---- v = xo ; sum(v) ----
  if (tid < P) vsm[tid] = xo;
  float sv = (tid < P) ? xo : 0.0f;
#pragma unroll
  for (int m = 32; m > 0; m >>= 1) sv += __shfl_down(sv, m);
  if (lane == 0) rs_wave[wv] = sv;
  __syncthreads();
  const float sumv = rs_wave[0] + rs_wave[1] + rs_wave[2] + rs_wave[3];

  // ---- test returns ----
  const float* __restrict__ Yte = Y + (size_t)(j + LAG_W) * STEPD * P;
  for (int d = wv; d < STEPD; d += 4) {
    float pp = Yte[(size_t)d * P + lane] * vsm[lane] +
               Yte[(size_t)d * P + 64 + lane] * vsm[64 + lane];
    for (int off = 32; off > 0; off >>= 1) pp += __shfl_down(pp, off);
    if (lane == 0) retd[d] = pp;
  }
  __syncthreads();

  if (tid == 0) {
    const float invs = 1.0f / sumv;
    float e = 0.0f, s = 0.0f;
#pragma unroll
    for (int d = 0; d < STEPD; ++d) {
      const float r = retd[d] * invs;
      e += r;
      s += r * r;
    }
    e_all[j] = e;
    s_all[j] = s * (1.0f / (float)STEPD);
  }
}

// ---------------- fallback: per-window full recompute (used if ws too small / odd shapes) ----------------
__global__ __launch_bounds__(256, 2) void window_fallback(
    const float* __restrict__ Y, const float* __restrict__ wbuf,
    const float* __restrict__ logridge, float* __restrict__ e_all,
    float* __restrict__ s_all, int W) {
  const int j = blockIdx.x;
  const int tid = threadIdx.x;
  const int ti = tid >> 4;
  const int tj = tid & 15;

  __shared__ float Msm[P][P + 1];
  __shared__ float wsm[T_WIN];
  __shared__ float swsm[T_WIN];
  __shared__ float meansm[P];
  __shared__ float red[256];
  __shared__ float retd[STEPD];
  __shared__ float zsm[P];
  __shared__ float vsm[P];
  __shared__ float bsm[P];

  float* stage = &Msm[0][0];

  for (int t = tid; t < T_WIN; t += 256) {
    wsm[t] = wbuf[t];
    swsm[t] = wbuf[T_WIN + t];
  }
  if (tid < P) bsm[tid] = 1.0f;
  const float denom = wbuf[960];
  const float ridge = expf(logridge[0]);
  __syncthreads();

  const float* __restrict__ Ywin = Y + (size_t)j * STEPD * P;
  {
    const int col = tid & 127;
    const int half = tid >> 7;
    float m = 0.0f;
    const int t0 = half * (T_WIN / 2), t1 = t0 + T_WIN / 2;
    for (int t = t0; t < t1; ++t) m += wsm[t] * Ywin[(size_t)t * P + col];
    red[tid] = m;
    __syncthreads();
    if (tid < P) meansm[tid] = (red[tid] + red[tid + 128]) * (1.0f / (float)T_WIN);
    __syncthreads();
  }

  float acc[8][8];
#pragma unroll
  for (int u = 0; u < 8; ++u)
#pragma unroll
    for (int v = 0; v < 8; ++v) acc[u][v] = 0.0f;

  for (int c = 0; c < T_WIN / 32; ++c) {
    __syncthreads();
#pragma unroll
    for (int i = 0; i < 4; ++i) {
      const int idx = i * 1024 + tid * 4;
      float4 v = *(const float4*)(Ywin + (size_t)c * 32 * P + idx);
      const float sw = swsm[c * 32 + (idx >> 7)];
      v.x *= sw; v.y *= sw; v.z *= sw; v.w *= sw;
      *(float4*)(stage + idx) = v;
    }
    __syncthreads();
#pragma unroll 4
    for (int t = 0; t < 32; ++t) {
      const float* rowp = stage + t * P;
      float af[8], bf[8];
      *(float4*)(af) = *(const float4*)(rowp + ti * 8);
      *(float4*)(af + 4) = *(const float4*)(rowp + ti * 8 + 4);
      *(float4*)(bf) = *(const float4*)(rowp + tj * 8);
      *(float4*)(bf + 4) = *(const float4*)(rowp + tj * 8 + 4);
#pragma unroll
      for (int u = 0; u < 8; ++u)
#pragma unroll
        for (int v = 0; v < 8; ++v) acc[u][v] += af[u] * bf[v];
    }
  }
  __syncthreads();

  const float invTd = 1.0f / ((float)T_WIN * denom);
#pragma unroll
  for (int u = 0; u < 8; ++u) {
    const int r = ti * 8 + u;
    const float mr = meansm[r];
#pragma unroll
    for (int v = 0; v < 8; ++v) {
      const int cc = tj * 8 + v;
      float m = (acc[u][v] - (float)T_WIN * mr * meansm[cc]) * invTd;
      if (r == cc) m += ridge;
      Msm[r][cc] = m;
    }
  }
  __syncthreads();

  for (int k = 0; k < P; ++k) {
    const float dkk = Msm[k][k];
    const float sq = sqrtf(dkk);
    const float invd = 1.0f / sq;
    if (tid == 0) Msm[k][k] = sq;
    const int i = k + 1 + tid;
    if (i < P) Msm[i][k] *= invd;
    __syncthreads();
    const int nrem = P - 1 - k;
    for (int ii = ti; ii < nrem; ii += 16) {
      const int ri = k + 1 + ii;
      const float Lik = Msm[ri][k];
      for (int jj = tj; jj < nrem; jj += 16) {
        const int cj = k + 1 + jj;
        Msm[ri][cj] -= Lik * Msm[cj][k];
      }
    }
    __syncthreads();
  }

  for (int k = 0; k < P; ++k) {
    const float zk = bsm[k] / Msm[k][k];
    if (tid == 0) zsm[k] = zk;
    const int i = k + 1 + tid;
    if (i < P) bsm[i] -= Msm[i][k] * zk;
    __syncthreads();
  }
  for (int k = P - 1; k >= 0; --k) {
    const float vk = zsm[k] / Msm[k][k];
    if (tid == 0) vsm[k] = vk;
    if (tid < k) zsm[tid] -= Msm[k][tid] * vk;
    __syncthreads();
  }

  red[tid] = (tid < P) ? vsm[tid] : 0.0f;
  __syncthreads();
  for (int off = 128; off > 0; off >>= 1) {
    if (tid < off) red[tid] += red[tid + off];
    __syncthreads();
  }

  const float* __restrict__ Yte = Y + (size_t)(j + LAG_W) * STEPD * P;
  const int wv = tid >> 6;
  const int lane = tid & 63;
  for (int d = wv; d < STEPD; d += 4) {
    float pp = Yte[(size_t)d * P + lane] * vsm[lane] +
               Yte[(size_t)d * P + 64 + lane] * vsm[64 + lane];
    for (int off = 32; off > 0; off >>= 1) pp += __shfl_down(pp, off);
    if (lane == 0) retd[d] = pp;
  }
  __syncthreads();

  if (tid == 0) {
    const float invs = 1.0f / red[0];
    float e = 0.0f, s = 0.0f;
#pragma unroll
    for (int d = 0; d < STEPD; ++d) {
      const float r = retd[d] * invs;
      e += r;
      s += r * r;
    }
    e_all[j] = e;
    s_all[j] = s * (1.0f / (float)STEPD);
  }
}

// ---------------- kernel 3: final reduction ----------------
__global__ __launch_bounds__(256) void final_kernel(const float* __restrict__ e_all,
                                                    const float* __restrict__ s_all,
                                                    float* __restrict__ out, int W) {
  __shared__ float r1[256], r2[256];
  const int tid = threadIdx.x;
  float e = 0.0f, s = 0.0f;
  for (int i = tid; i < W; i += 256) {
    e += e_all[i];
    s += s_all[i];
  }
  r1[tid] = e;
  r2[tid] = s;
  __syncthreads();
  for (int off = 128; off > 0; off >>= 1) {
    if (tid < off) {
      r1[tid] += r1[tid + off];
      r2[tid] += r2[tid + off];
    }
    __syncthreads();
  }
  if (tid == 0) {
    const float vol = sqrtf(r2[0] / (float)W * 252.0f);
    const float mu = r1[0] / (float)W / (float)STEPD * 252.0f;
    out[0] = vol;
    out[1] = mu;
    out[2] = mu / vol;
  }
}

extern "C" void kernel_launch(void* const* d_in, const int* in_sizes, int n_in,
                              void* d_out, int out_size, void* d_ws, size_t ws_size,
                              hipStream_t stream) {
  const float* Y = (const float*)d_in[0];
  const float* a = (const float*)d_in[1];
  const float* logridge = (const float*)d_in[2];
  float* out = (float*)d_out;

  const int n = in_sizes[0] / P;     // 20480 days
  const int K = n / STEPD;           // 1024 blocks
  const int W = K - LAG_W;           // 1000 windows

  float* ws = (float*)d_ws;
  float* wbuf = ws;                  // 2048 floats
  float* e_all = ws + 2048;          // W (<=1024)
  float* s_all = ws + 3072;          // W
  float* cvec = ws + 4096;           // K*128
  float* Gall = ws + 4096 + (size_t)K * P;  // K*128*128 (C, then scanned in place)

  const size_t need = ((size_t)4096 + (size_t)K * P + (size_t)K * P * P) * sizeof(float);

  weights_kernel<<<1, 512, 0, stream>>>(a, wbuf);
  if (ws_size >= need && (n % STEPD) == 0 && W > 0 && W <= 1024 && (K % SEG) == 0) {
    cblocks_kernel<<<K, 256, 0, stream>>>(Y, wbuf, cvec, Gall, K);
    scan_kernel<<<(K / SEG) * 64, 256, 0, stream>>>(Gall, wbuf);
    window5_kernel<<<W, 256, 0, stream>>>(Y, wbuf, logridge, cvec, Gall, e_all, s_all, W);
  } else {
    window_fallback<<<W, 256, 0, stream>>>(Y, wbuf, logridge, e_all, s_all, W);
  }
  final_kernel<<<1, 256, 0, stream>>>(e_all, s_all, out, W);
}

// Round 7
// 133.605 us; speedup vs baseline: 6.5854x; 1.1924x over previous
//
#include <hip/hip_runtime.h>
#include <math.h>

#define P 128
#define T_WIN 480
#define STEPD 20
#define LAG_W 24
#define NITER 24
#define SEG 128

// wbuf layout (floats, 2048 total):
// [0..479]=w_norm  [480..959]=sqrt(w_norm)  [960]=denom  [961]=S
// [962..985]=coef_m=a^(20(23-m))  [986..1005]=sqrt(bw_d)=sqrt(a^(19-d))
// [1024..1174]=pw20[x]=a^(20x), x=0..150   [1280..1407]=ainvt[k]=a^(-20k), k=0..127
#define SBW_OFF 986
#define PW20_OFF 1024
#define AINVT_OFF 1280

// ---------------- kernel 0: EWMA weights (fp64, one block) ----------------
__global__ __launch_bounds__(512) void weights_kernel(const float* __restrict__ a,
                                                      float* __restrict__ wbuf) {
  __shared__ double redd[512];
  const int t = threadIdx.x;
  const double la = log((double)a[0]);
  const double u = (t < T_WIN) ? exp((double)(T_WIN - 1 - t) * la) : 0.0;
  redd[t] = u;
  __syncthreads();
  for (int off = 256; off > 0; off >>= 1) {
    if (t < off) redd[t] += redd[t + off];
    __syncthreads();
  }
  const double S = redd[0];
  __syncthreads();
  redd[t] = u * u;
  __syncthreads();
  for (int off = 256; off > 0; off >>= 1) {
    if (t < off) redd[t] += redd[t + off];
    __syncthreads();
  }
  const double Su2 = redd[0];
  if (t < T_WIN) {
    const double wn = u / S * (double)T_WIN;
    wbuf[t] = (float)wn;
    wbuf[T_WIN + t] = (float)sqrt(wn);
  }
  if (t == 0) {
    wbuf[960] = (float)(1.0 - Su2 / (S * S));
    wbuf[961] = (float)S;
  }
  if (t < LAG_W) wbuf[962 + t] = (float)exp((double)(STEPD * (LAG_W - 1 - t)) * la);
  if (t < STEPD) wbuf[SBW_OFF + t] = (float)exp(0.5 * (double)(STEPD - 1 - t) * la);
  if (t < 151) wbuf[PW20_OFF + t] = (float)exp((double)(20 * t) * la);
  if (t < SEG) wbuf[AINVT_OFF + t] = (float)exp(-(double)(20 * t) * la);
}

// ---------------- kernel 1: per-20-day-block outer products ----------------
__global__ __launch_bounds__(256) void cblocks_kernel(const float* __restrict__ Y,
                                                      const float* __restrict__ wbuf,
                                                      float* __restrict__ cvec,
                                                      float* __restrict__ Call, int K) {
  const int k = blockIdx.x;
  const int tid = threadIdx.x;
  const int ti = tid >> 4, tj = tid & 15;
  __shared__ float st[STEPD][P];
  __shared__ float sbwsm[STEPD];
  if (tid < STEPD) sbwsm[tid] = wbuf[SBW_OFF + tid];
  __syncthreads();
  const float* __restrict__ Yb = Y + (size_t)k * STEPD * P;
  for (int i = tid; i < STEPD * P / 4; i += 256) {
    float4 v = ((const float4*)Yb)[i];
    const float sw = sbwsm[i >> 5];
    v.x *= sw; v.y *= sw; v.z *= sw; v.w *= sw;
    ((float4*)&st[0][0])[i] = v;
  }
  __syncthreads();

  float acc[8][8];
#pragma unroll
  for (int u = 0; u < 8; ++u)
#pragma unroll
    for (int v = 0; v < 8; ++v) acc[u][v] = 0.0f;

#pragma unroll 4
  for (int t = 0; t < STEPD; ++t) {
    float af[8], bf[8];
    *(float4*)(af)     = *(const float4*)&st[t][ti * 4];
    *(float4*)(af + 4) = *(const float4*)&st[t][64 + ti * 4];
    *(float4*)(bf)     = *(const float4*)&st[t][tj * 4];
    *(float4*)(bf + 4) = *(const float4*)&st[t][64 + tj * 4];
#pragma unroll
    for (int u = 0; u < 8; ++u)
#pragma unroll
      for (int v = 0; v < 8; ++v) acc[u][v] += af[u] * bf[v];
  }

  float* __restrict__ Ck = Call + (size_t)k * (P * P);
#pragma unroll
  for (int u = 0; u < 8; ++u) {
    const int r = (u < 4) ? (ti * 4 + u) : (64 + ti * 4 + u - 4);
    float4 o0, o1;
    o0.x = acc[u][0]; o0.y = acc[u][1]; o0.z = acc[u][2]; o0.w = acc[u][3];
    o1.x = acc[u][4]; o1.y = acc[u][5]; o1.z = acc[u][6]; o1.w = acc[u][7];
    *(float4*)(Ck + r * P + tj * 4) = o0;
    *(float4*)(Ck + r * P + 64 + tj * 4) = o1;
  }
  if (tid < P) {
    float s = 0.0f;
    for (int t = 0; t < STEPD; ++t) s += sbwsm[t] * st[t][tid];
    cvec[(size_t)k * P + tid] = s;
  }
}

// ---------------- kernel 1.5: segmented weighted prefix scan (in place) ----------------
__global__ __launch_bounds__(256) void scan_kernel(float* __restrict__ Call,
                                                   const float* __restrict__ wbuf) {
  __shared__ float asm_[SEG];
  const int tid = threadIdx.x;
  const int seg = blockIdx.x >> 6;
  const int chunk = blockIdx.x & 63;
  if (tid < SEG) asm_[tid] = wbuf[AINVT_OFF + tid];
  __syncthreads();
  const int e = chunk * 256 + tid;
  float* __restrict__ base = Call + ((size_t)seg * SEG) * (P * P) + e;
  float g = 0.0f;
#pragma unroll 4
  for (int k = 0; k < SEG; ++k) {
    const float c = base[(size_t)k * (P * P)];
    g = fmaf(asm_[k], c, g);
    base[(size_t)k * (P * P)] = g;
  }
}

// ---------------- kernel 2: TWO windows per block; CG chains interleaved ----------------
__global__ __launch_bounds__(256, 2) void window6_kernel(
    const float* __restrict__ Y, const float* __restrict__ wbuf,
    const float* __restrict__ logridge, const float* __restrict__ cvec,
    const float* __restrict__ Gall, float* __restrict__ e_all,
    float* __restrict__ s_all, int W, int nb) {
  const int bid = blockIdx.x;
  const int q = nb >> 3, r = nb & 7;
  const int xcd = bid & 7, idx = bid >> 3;
  const int wg = ((xcd < r) ? (xcd * (q + 1)) : (r * (q + 1) + (xcd - r) * q)) + idx;
  const int jA = 2 * wg;
  const int jB = (jA + 1 < W) ? (jA + 1) : jA;

  const int tid = threadIdx.x;
  const int ti = tid >> 4, tj = tid & 15;
  const int lane = tid & 63;
  const int wv = tid >> 6;

  __shared__ float psmA[P], psmB[P];
  __shared__ float ApsmA[P], ApsmB[P];
  __shared__ float vsmA[P], vsmB[P];
  __shared__ float meansmA[P], meansmB[P];
  __shared__ float coefsm[LAG_W];
  __shared__ float pap_waveA[4], pap_waveB[4];
  __shared__ float rs_waveA[4], rs_waveB[4];
  __shared__ float retdA[STEPD], retdB[STEPD];

  if (tid < LAG_W) coefsm[tid] = wbuf[962 + tid];
  __syncthreads();

  const float S = wbuf[961];
  const float denom = wbuf[960];
  const float ridge = expf(logridge[0]);

  int rowi[8], rowoff[8];
#pragma unroll
  for (int u = 0; u < 8; ++u) {
    rowi[u] = (u < 4) ? (ti * 4 + u) : (64 + ti * 4 + u - 4);
    rowoff[u] = rowi[u] * P + tj * 4;
  }

  // ---- G-difference plans for both windows ----
  int matsA[3], matsB[3];
  float sclsA[3], sclsB[3];
  int nmA = 0, nmB = 0;
  {
    const int o1 = jA & ~(SEG - 1);
    const int end = jA + 23;
    const int b = o1 + SEG;
    const float pA = wbuf[PW20_OFF + (end - o1)];
    if (end < b) {
      matsA[nmA] = end; sclsA[nmA] = pA; ++nmA;
      if (jA > o1) { matsA[nmA] = jA - 1; sclsA[nmA] = -pA; ++nmA; }
    } else {
      const float pB2 = wbuf[PW20_OFF + (end - b)];
      matsA[nmA] = b - 1; sclsA[nmA] = pA; ++nmA;
      if (jA > o1) { matsA[nmA] = jA - 1; sclsA[nmA] = -pA; ++nmA; }
      matsA[nmA] = end; sclsA[nmA] = pB2; ++nmA;
    }
  }
  {
    const int o1 = jB & ~(SEG - 1);
    const int end = jB + 23;
    const int b = o1 + SEG;
    const float pA = wbuf[PW20_OFF + (end - o1)];
    if (end < b) {
      matsB[nmB] = end; sclsB[nmB] = pA; ++nmB;
      if (jB > o1) { matsB[nmB] = jB - 1; sclsB[nmB] = -pA; ++nmB; }
    } else {
      const float pB2 = wbuf[PW20_OFF + (end - b)];
      matsB[nmB] = b - 1; sclsB[nmB] = pA; ++nmB;
      if (jB > o1) { matsB[nmB] = jB - 1; sclsB[nmB] = -pB2 * 0.0f - pA; ++nmB; }  // -pA
      matsB[nmB] = end; sclsB[nmB] = pB2; ++nmB;
    }
  }

  // ---- Araw accumulation (both windows, registers) ----
  float accA[8][8], accB[8][8];
#pragma unroll
  for (int u = 0; u < 8; ++u)
#pragma unroll
    for (int v = 0; v < 8; ++v) { accA[u][v] = 0.0f; accB[u][v] = 0.0f; }

  for (int m = 0; m < nmA; ++m) {
    const float cf = sclsA[m];
    const float* __restrict__ Gm = Gall + (size_t)matsA[m] * (P * P);
#pragma unroll
    for (int u = 0; u < 8; ++u) {
      const float4 t0 = *(const float4*)(Gm + rowoff[u]);
      const float4 t1 = *(const float4*)(Gm + rowoff[u] + 64);
      accA[u][0] += cf * t0.x; accA[u][1] += cf * t0.y;
      accA[u][2] += cf * t0.z; accA[u][3] += cf * t0.w;
      accA[u][4] += cf * t1.x; accA[u][5] += cf * t1.y;
      accA[u][6] += cf * t1.z; accA[u][7] += cf * t1.w;
    }
  }
  for (int m = 0; m < nmB; ++m) {
    const float cf = sclsB[m];
    const float* __restrict__ Gm = Gall + (size_t)matsB[m] * (P * P);
#pragma unroll
    for (int u = 0; u < 8; ++u) {
      const float4 t0 = *(const float4*)(Gm + rowoff[u]);
      const float4 t1 = *(const float4*)(Gm + rowoff[u] + 64);
      accB[u][0] += cf * t0.x; accB[u][1] += cf * t0.y;
      accB[u][2] += cf * t0.z; accB[u][3] += cf * t0.w;
      accB[u][4] += cf * t1.x; accB[u][5] += cf * t1.y;
      accB[u][6] += cf * t1.z; accB[u][7] += cf * t1.w;
    }
  }

  // ---- mraw for both windows (halves of the block in parallel) ----
  if (tid < P) {
    float s = 0.0f;
    for (int m = 0; m < LAG_W; ++m) s += coefsm[m] * cvec[(size_t)(jA + m) * P + tid];
    meansmA[tid] = s;
  } else {
    const int t2 = tid - P;
    float s = 0.0f;
    for (int m = 0; m < LAG_W; ++m) s += coefsm[m] * cvec[(size_t)(jB + m) * P + t2];
    meansmB[t2] = s;
  }
  if (tid < P) { psmA[tid] = 1.0f; psmB[tid] = 1.0f; }
  __syncthreads();

  // ---- M (registers) for both ----
  {
    const float sc1 = 1.0f / (S * denom);
    const float sc2 = 1.0f / (S * S * denom);
#pragma unroll
    for (int u = 0; u < 8; ++u) {
      const int rr = rowi[u];
      const float mrA = meansmA[rr] * sc2;
      const float mrB = meansmB[rr] * sc2;
#pragma unroll
      for (int v = 0; v < 8; ++v) {
        const int c = (v < 4) ? (tj * 4 + v) : (64 + tj * 4 + (v - 4));
        float mA = accA[u][v] * sc1 - mrA * meansmA[c];
        float mB = accB[u][v] * sc1 - mrB * meansmB[c];
        if (rr == c) { mA += ridge; mB += ridge; }
        accA[u][v] = mA;
        accB[u][v] = mB;
      }
    }
  }

  // ---- dual CG: M_A vA = 1, M_B vB = 1 ----
  float xoA = 0.0f, roA = 1.0f, poA = 1.0f, rsA = (float)P;
  float xoB = 0.0f, roB = 1.0f, poB = 1.0f, rsB = (float)P;

  for (int it = 0; it < NITER; ++it) {
    const float4 a0 = *(const float4*)&psmA[tj * 4];
    const float4 a1 = *(const float4*)&psmA[64 + tj * 4];
    const float4 b0 = *(const float4*)&psmB[tj * 4];
    const float4 b1 = *(const float4*)&psmB[64 + tj * 4];
    float pvA[8] = {a0.x, a0.y, a0.z, a0.w, a1.x, a1.y, a1.z, a1.w};
    float pvB[8] = {b0.x, b0.y, b0.z, b0.w, b1.x, b1.y, b1.z, b1.w};
    float apA[8], apB[8];
#pragma unroll
    for (int u = 0; u < 8; ++u) {
      float sA = 0.0f, sB = 0.0f;
#pragma unroll
      for (int v = 0; v < 8; ++v) { sA += accA[u][v] * pvA[v]; sB += accB[u][v] * pvB[v]; }
      apA[u] = sA; apB[u] = sB;
    }
#pragma unroll
    for (int m = 1; m <= 8; m <<= 1) {
#pragma unroll
      for (int u = 0; u < 8; ++u) {
        apA[u] += __shfl_xor(apA[u], m);
        apB[u] += __shfl_xor(apB[u], m);
      }
    }
    if (tj == 0) {
      float papA = 0.0f, papB = 0.0f;
#pragma unroll
      for (int u = 0; u < 8; ++u) {
        ApsmA[rowi[u]] = apA[u]; papA += apA[u] * psmA[rowi[u]];
        ApsmB[rowi[u]] = apB[u]; papB += apB[u] * psmB[rowi[u]];
      }
      papA += __shfl_down(papA, 16); papB += __shfl_down(papB, 16);
      papA += __shfl_down(papA, 32); papB += __shfl_down(papB, 32);
      if (lane == 0) { pap_waveA[wv] = papA; pap_waveB[wv] = papB; }
    }
    __syncthreads();  // B1

    const float papAt = pap_waveA[0] + pap_waveA[1] + pap_waveA[2] + pap_waveA[3];
    const float papBt = pap_waveB[0] + pap_waveB[1] + pap_waveB[2] + pap_waveB[3];
    const float alA = rsA / papAt;
    const float alB = rsB / papBt;
    float rspA = 0.0f, rspB = 0.0f;
    if (tid < P) {
      xoA += alA * poA; roA -= alA * ApsmA[tid]; rspA = roA * roA;
      xoB += alB * poB; roB -= alB * ApsmB[tid]; rspB = roB * roB;
    }
#pragma unroll
    for (int m = 32; m > 0; m >>= 1) {
      rspA += __shfl_down(rspA, m);
      rspB += __shfl_down(rspB, m);
    }
    if (lane == 0) { rs_waveA[wv] = rspA; rs_waveB[wv] = rspB; }
    __syncthreads();  // B2

    const float rsnA = rs_waveA[0] + rs_waveA[1] + rs_waveA[2] + rs_waveA[3];
    const float rsnB = rs_waveB[0] + rs_waveB[1] + rs_waveB[2] + rs_waveB[3];
    const float beA = rsnA / rsA;
    const float beB = rsnB / rsB;
    rsA = rsnA; rsB = rsnB;
    if (tid < P) {
      poA = roA + beA * poA; psmA[tid] = poA;
      poB = roB + beB * poB; psmB[tid] = poB;
    }
    __syncthreads();  // B3
  }

  // ---- publish v, sum(v) for both ----
  float svA = 0.0f, svB = 0.0f;
  if (tid < P) {
    vsmA[tid] = xoA; vsmB[tid] = xoB;
    svA = xoA; svB = xoB;
  }
#pragma unroll
  for (int m = 32; m > 0; m >>= 1) {
    svA += __shfl_down(svA, m);
    svB += __shfl_down(svB, m);
  }
  if (lane == 0) { rs_waveA[wv] = svA; rs_waveB[wv] = svB; }
  __syncthreads();
  const float sumvA = rs_waveA[0] + rs_waveA[1] + rs_waveA[2] + rs_waveA[3];
  const float sumvB = rs_waveB[0] + rs_waveB[1] + rs_waveB[2] + rs_waveB[3];

  // ---- test returns for both windows ----
  const float* __restrict__ YteA = Y + (size_t)(jA + LAG_W) * STEPD * P;
  const float* __restrict__ YteB = Y + (size_t)(jB + LAG_W) * STEPD * P;
  for (int d = wv; d < STEPD; d += 4) {
    float pA = YteA[(size_t)d * P + lane] * vsmA[lane] +
               YteA[(size_t)d * P + 64 + lane] * vsmA[64 + lane];
    float pB = YteB[(size_t)d * P + lane] * vsmB[lane] +
               YteB[(size_t)d * P + 64 + lane] * vsmB[64 + lane];
    for (int off = 32; off > 0; off >>= 1) {
      pA += __shfl_down(pA, off);
      pB += __shfl_down(pB, off);
    }
    if (lane == 0) { retdA[d] = pA; retdB[d] = pB; }
  }
  __syncthreads();

  if (tid == 0) {
    const float invs = 1.0f / sumvA;
    float e = 0.0f, s = 0.0f;
#pragma unroll
    for (int d = 0; d < STEPD; ++d) {
      const float rr = retdA[d] * invs;
      e += rr; s += rr * rr;
    }
    e_all[jA] = e;
    s_all[jA] = s * (1.0f / (float)STEPD);
  } else if (tid == 64) {
    const float invs = 1.0f / sumvB;
    float e = 0.0f, s = 0.0f;
#pragma unroll
    for (int d = 0; d < STEPD; ++d) {
      const float rr = retdB[d] * invs;
      e += rr; s += rr * rr;
    }
    e_all[jB] = e;
    s_all[jB] = s * (1.0f / (float)STEPD);
  }
}

// ---------------- fallback: per-window full recompute ----------------
__global__ __launch_bounds__(256, 2) void window_fallback(
    const float* __restrict__ Y, const float* __restrict__ wbuf,
    const float* __restrict__ logridge, float* __restrict__ e_all,
    float* __restrict__ s_all, int W) {
  const int j = blockIdx.x;
  const int tid = threadIdx.x;
  const int ti = tid >> 4;
  const int tj = tid & 15;

  __shared__ float Msm[P][P + 1];
  __shared__ float wsm[T_WIN];
  __shared__ float swsm[T_WIN];
  __shared__ float meansm[P];
  __shared__ float red[256];
  __shared__ float retd[STEPD];
  __shared__ float zsm[P];
  __shared__ float vsm[P];
  __shared__ float bsm[P];

  float* stage = &Msm[0][0];

  for (int t = tid; t < T_WIN; t += 256) {
    wsm[t] = wbuf[t];
    swsm[t] = wbuf[T_WIN + t];
  }
  if (tid < P) bsm[tid] = 1.0f;
  const float denom = wbuf[960];
  const float ridge = expf(logridge[0]);
  __syncthreads();

  const float* __restrict__ Ywin = Y + (size_t)j * STEPD * P;
  {
    const int col = tid & 127;
    const int half = tid >> 7;
    float m = 0.0f;
    const int t0 = half * (T_WIN / 2), t1 = t0 + T_WIN / 2;
    for (int t = t0; t < t1; ++t) m += wsm[t] * Ywin[(size_t)t * P + col];
    red[tid] = m;
    __syncthreads();
    if (tid < P) meansm[tid] = (red[tid] + red[tid + 128]) * (1.0f / (float)T_WIN);
    __syncthreads();
  }

  float acc[8][8];
#pragma unroll
  for (int u = 0; u < 8; ++u)
#pragma unroll
    for (int v = 0; v < 8; ++v) acc[u][v] = 0.0f;

  for (int c = 0; c < T_WIN / 32; ++c) {
    __syncthreads();
#pragma unroll
    for (int i = 0; i < 4; ++i) {
      const int idx = i * 1024 + tid * 4;
      float4 v = *(const float4*)(Ywin + (size_t)c * 32 * P + idx);
      const float sw = swsm[c * 32 + (idx >> 7)];
      v.x *= sw; v.y *= sw; v.z *= sw; v.w *= sw;
      *(float4*)(stage + idx) = v;
    }
    __syncthreads();
#pragma unroll 4
    for (int t = 0; t < 32; ++t) {
      const float* rowp = stage + t * P;
      float af[8], bf[8];
      *(float4*)(af) = *(const float4*)(rowp + ti * 8);
      *(float4*)(af + 4) = *(const float4*)(rowp + ti * 8 + 4);
      *(float4*)(bf) = *(const float4*)(rowp + tj * 8);
      *(float4*)(bf + 4) = *(const float4*)(rowp + tj * 8 + 4);
#pragma unroll
      for (int u = 0; u < 8; ++u)
#pragma unroll
        for (int v = 0; v < 8; ++v) acc[u][v] += af[u] * bf[v];
    }
  }
  __syncthreads();

  const float invTd = 1.0f / ((float)T_WIN * denom);
#pragma unroll
  for (int u = 0; u < 8; ++u) {
    const int r = ti * 8 + u;
    const float mr = meansm[r];
#pragma unroll
    for (int v = 0; v < 8; ++v) {
      const int cc = tj * 8 + v;
      float m = (acc[u][v] - (float)T_WIN * mr * meansm[cc]) * invTd;
      if (r == cc) m += ridge;
      Msm[r][cc] = m;
    }
  }
  __syncthreads();

  for (int k = 0; k < P; ++k) {
    const float dkk = Msm[k][k];
    const float sq = sqrtf(dkk);
    const float invd = 1.0f / sq;
    if (tid == 0) Msm[k][k] = sq;
    const int i = k + 1 + tid;
    if (i < P) Msm[i][k] *= invd;
    __syncthreads();
    const int nrem = P - 1 - k;
    for (int ii = ti; ii < nrem; ii += 16) {
      const int ri = k + 1 + ii;
      const float Lik = Msm[ri][k];
      for (int jj = tj; jj < nrem; jj += 16) {
        const int cj = k + 1 + jj;
        Msm[ri][cj] -= Lik * Msm[cj][k];
      }
    }
    __syncthreads();
  }

  for (int k = 0; k < P; ++k) {
    const float zk = bsm[k] / Msm[k][k];
    if (tid == 0) zsm[k] = zk;
    const int i = k + 1 + tid;
    if (i < P) bsm[i] -= Msm[i][k] * zk;
    __syncthreads();
  }
  for (int k = P - 1; k >= 0; --k) {
    const float vk = zsm[k] / Msm[k][k];
    if (tid == 0) vsm[k] = vk;
    if (tid < k) zsm[tid] -= Msm[k][tid] * vk;
    __syncthreads();
  }

  red[tid] = (tid < P) ? vsm[tid] : 0.0f;
  __syncthreads();
  for (int off = 128; off > 0; off >>= 1) {
    if (tid < off) red[tid] += red[tid + off];
    __syncthreads();
  }

  const float* __restrict__ Yte = Y + (size_t)(j + LAG_W) * STEPD * P;
  const int wv = tid >> 6;
  const int lane = tid & 63;
  for (int d = wv; d < STEPD; d += 4) {
    float pp = Yte[(size_t)d * P + lane] * vsm[lane] +
               Yte[(size_t)d * P + 64 + lane] * vsm[64 + lane];
    for (int off = 32; off > 0; off >>= 1) pp += __shfl_down(pp, off);
    if (lane == 0) retd[d] = pp;
  }
  __syncthreads();

  if (tid == 0) {
    const float invs = 1.0f / red[0];
    float e = 0.0f, s = 0.0f;
#pragma unroll
    for (int d = 0; d < STEPD; ++d) {
      const float r = retd[d] * invs;
      e += r;
      s += r * r;
    }
    e_all[j] = e;
    s_all[j] = s * (1.0f / (float)STEPD);
  }
}

// ---------------- kernel 3: final reduction ----------------
__global__ __launch_bounds__(256) void final_kernel(const float* __restrict__ e_all,
                                                    const float* __restrict__ s_all,
                                                    float* __restrict__ out, int W) {
  __shared__ float r1[256], r2[256];
  const int tid = threadIdx.x;
  float e = 0.0f, s = 0.0f;
  for (int i = tid; i < W; i += 256) {
    e += e_all[i];
    s += s_all[i];
  }
  r1[tid] = e;
  r2[tid] = s;
  __syncthreads();
  for (int off = 128; off > 0; off >>= 1) {
    if (tid < off) {
      r1[tid] += r1[tid + off];
      r2[tid] += r2[tid + off];
    }
    __syncthreads();
  }
  if (tid == 0) {
    const float vol = sqrtf(r2[0] / (float)W * 252.0f);
    const float mu = r1[0] / (float)W / (float)STEPD * 252.0f;
    out[0] = vol;
    out[1] = mu;
    out[2] = mu / vol;
  }
}

extern "C" void kernel_launch(void* const* d_in, const int* in_sizes, int n_in,
                              void* d_out, int out_size, void* d_ws, size_t ws_size,
                              hipStream_t stream) {
  const float* Y = (const float*)d_in[0];
  const float* a = (const float*)d_in[1];
  const float* logridge = (const float*)d_in[2];
  float* out = (float*)d_out;

  const int n = in_sizes[0] / P;     // 20480 days
  const int K = n / STEPD;           // 1024 blocks
  const int W = K - LAG_W;           // 1000 windows

  float* ws = (float*)d_ws;
  float* wbuf = ws;                  // 2048 floats
  float* e_all = ws + 2048;          // W (<=1024)
  float* s_all = ws + 3072;          // W
  float* cvec = ws + 4096;           // K*128
  float* Gall = ws + 4096 + (size_t)K * P;  // K*128*128 (C, then scanned in place)

  const size_t need = ((size_t)4096 + (size_t)K * P + (size_t)K * P * P) * sizeof(float);

  weights_kernel<<<1, 512, 0, stream>>>(a, wbuf);
  if (ws_size >= need && (n % STEPD) == 0 && W > 0 && W <= 1024 && (K % SEG) == 0) {
    const int nb = (W + 1) >> 1;
    cblocks_kernel<<<K, 256, 0, stream>>>(Y, wbuf, cvec, Gall, K);
    scan_kernel<<<(K / SEG) * 64, 256, 0, stream>>>(Gall, wbuf);
    window6_kernel<<<nb, 256, 0, stream>>>(Y, wbuf, logridge, cvec, Gall, e_all, s_all, W, nb);
  } else {
    window_fallback<<<W, 256, 0, stream>>>(Y, wbuf, logridge, e_all, s_all, W);
  }
  final_kernel<<<1, 256, 0, stream>>>(e_all, s_all, out, W);
}